// Round 2
// baseline (99.917 us; speedup 1.0000x reference)
//
#include <hip/hip_runtime.h>
#include <hip/hip_bf16.h>

#define B_   64
#define NL_  128
#define NP_  128
#define E_   4096

// ---------------------------------------------------------------------------
// ws layout (bytes):
//   [0, 4194304)          Q f32 [B][NL][NP]      (4 MB)
//   [4194304, +2048)      num_part[512] f32      (one per k_edges block)
//   [4196352, +2048)      den_part[512] f32
// ---------------------------------------------------------------------------

// K1: Q = P @ A_fid, with A_fid built in-LDS per block from d_hw/d_error.
// 512 blocks x 16 rows. 256 threads: thread tile = 2 rows x 4 cols.
__global__ __launch_bounds__(256) void k_qgemm(
    const float* __restrict__ P,
    const float* __restrict__ d_error,
    const int*   __restrict__ d_hw,
    float* __restrict__ Q)
{
    __shared__ float As[NP_ * NP_];            // 64 KB
    const int t = threadIdx.x;

    // Build A_fid[16384] cooperatively: 16 float4 per thread, coalesced.
    const float4* de4 = (const float4*)d_error;
    const int4*   dh4 = (const int4*)d_hw;
    float4* As4 = (float4*)As;
    #pragma unroll
    for (int k = 0; k < 16; ++k) {
        int f = k*256 + t;
        float4 e = de4[f];
        int4   h = dh4[f];
        float4 a;
        a.x = (h.x == 1) ? fmaxf(1.0f - e.x, 0.0f) : 0.0f;
        a.y = (h.y == 1) ? fmaxf(1.0f - e.y, 0.0f) : 0.0f;
        a.z = (h.z == 1) ? fmaxf(1.0f - e.z, 0.0f) : 0.0f;
        a.w = (h.w == 1) ? fmaxf(1.0f - e.w, 0.0f) : 0.0f;
        As4[f] = a;
    }
    __syncthreads();

    const int row0 = blockIdx.x * 16;          // grid 512 -> 8192 rows
    const int tc = t & 31;                     // col group: 4 cols at 4*tc
    const int tr = t >> 5;                     // 8 row groups x 2 rows
    const float* Pr0 = P + (row0 + 2*tr + 0) * NP_;
    const float* Pr1 = P + (row0 + 2*tr + 1) * NP_;

    float4 acc0 = {0,0,0,0}, acc1 = {0,0,0,0};
    const float4* As4r = (const float4*)As;
    #pragma unroll 8
    for (int p = 0; p < NP_; ++p) {
        float4 av = As4r[p*32 + tc];
        float pv0 = Pr0[p];
        float pv1 = Pr1[p];
        acc0.x = fmaf(pv0, av.x, acc0.x); acc0.y = fmaf(pv0, av.y, acc0.y);
        acc0.z = fmaf(pv0, av.z, acc0.z); acc0.w = fmaf(pv0, av.w, acc0.w);
        acc1.x = fmaf(pv1, av.x, acc1.x); acc1.y = fmaf(pv1, av.y, acc1.y);
        acc1.z = fmaf(pv1, av.z, acc1.z); acc1.w = fmaf(pv1, av.w, acc1.w);
    }
    float4* Q4 = (float4*)(Q + row0 * NP_);
    Q4[(2*tr+0)*32 + tc] = acc0;
    Q4[(2*tr+1)*32 + tc] = acc1;
}

// K2: per-edge score = dot(Q[b,i,:], P[b,j,:]); per-block partials, no atomics.
// 512 blocks = 64 batches x 8 chunks; 32 lanes per edge, 8 edges in flight/block.
__global__ __launch_bounds__(256) void k_edges(
    const float* __restrict__ P,
    const float* __restrict__ Q,
    const float* __restrict__ ew,
    const int*   __restrict__ pairs_raw,
    float* __restrict__ num_part,
    float* __restrict__ den_part)
{
    const int b     = blockIdx.x >> 3;
    const int chunk = blockIdx.x & 7;
    const int t = threadIdx.x;
    const int g = t >> 5;                       // 8 edge-groups per block
    const int c = t & 31;

    // int64-vs-int32 detection: if values are int64, the high word of each of
    // the first 64 values (odd int32 positions) is 0. One load + ballot.
    int hw = pairs_raw[2*(t & 63) + 1];
    unsigned long long nz = __ballot(hw != 0);
    const int is64 = (nz == 0ULL);

    const float4* Q4 = (const float4*)(Q + (size_t)b * NL_ * NP_);
    const float4* P4 = (const float4*)(P + (size_t)b * NL_ * NP_);
    const float*  wrow = ew + b * E_;

    float acc  = 0.0f;
    float wacc = 0.0f;
    const int ebase = chunk * 512;
    #pragma unroll 8
    for (int k = 0; k < 64; ++k) {
        int e = ebase + k*8 + g;
        long pe = (long)b * E_ + e;
        int i, j;
        if (is64) { i = pairs_raw[4*pe];  j = pairs_raw[4*pe + 2]; }
        else      { i = pairs_raw[2*pe];  j = pairs_raw[2*pe + 1]; }
        float w = wrow[e];
        float4 qv = Q4[i*32 + c];
        float4 pv = P4[j*32 + c];
        acc = fmaf(w, qv.x*pv.x + qv.y*pv.y + qv.z*pv.z + qv.w*pv.w, acc);
        if (c == 0) wacc += w;
    }
    #pragma unroll
    for (int off = 32; off >= 1; off >>= 1) {
        acc  += __shfl_xor(acc,  off, 64);
        wacc += __shfl_xor(wacc, off, 64);
    }
    __shared__ float rs[8];
    const int wid  = t >> 6;
    const int lane = t & 63;
    if (lane == 0) { rs[wid] = acc; rs[4 + wid] = wacc; }
    __syncthreads();
    if (t == 0) {
        num_part[blockIdx.x] = rs[0] + rs[1] + rs[2] + rs[3];
        den_part[blockIdx.x] = rs[4] + rs[5] + rs[6] + rs[7];
    }
}

// K3: loss = -(1/B) * sum_b (sum_c num[b,c]) / max(sum_c den[b,c], 1e-8)
__global__ __launch_bounds__(64) void k_final(
    const float* __restrict__ num_part,
    const float* __restrict__ den_part,
    float* __restrict__ out)
{
    int b = threadIdx.x;                        // 64 threads, one per batch
    float n = 0.0f, d = 0.0f;
    #pragma unroll
    for (int c = 0; c < 8; ++c) {
        n += num_part[b*8 + c];
        d += den_part[b*8 + c];
    }
    float v = n / fmaxf(d, 1e-8f);
    #pragma unroll
    for (int off = 32; off >= 1; off >>= 1) v += __shfl_xor(v, off, 64);
    if (b == 0) out[0] = -v / (float)B_;
}

extern "C" void kernel_launch(void* const* d_in, const int* in_sizes, int n_in,
                              void* d_out, int out_size, void* d_ws, size_t ws_size,
                              hipStream_t stream) {
    const float* P       = (const float*)d_in[0];
    const float* d_error = (const float*)d_in[1];
    const float* ew      = (const float*)d_in[2];
    const int*   d_hw    = (const int*)d_in[3];
    const int*   pairs   = (const int*)d_in[4];
    float* out = (float*)d_out;

    char*  ws  = (char*)d_ws;
    float* Q   = (float*)ws;
    float* num = (float*)(ws + 4194304);
    float* den = (float*)(ws + 4194304 + 2048);

    k_qgemm<<<512, 256, 0, stream>>>(P, d_error, d_hw, Q);
    k_edges<<<512, 256, 0, stream>>>(P, Q, ew, pairs, num, den);
    k_final<<<1,   64,  0, stream>>>(num, den, out);
}

// Round 3
// 96.994 us; speedup vs baseline: 1.0301x; 1.0301x over previous
//
#include <hip/hip_runtime.h>
#include <hip/hip_bf16.h>

#define B_   64
#define NL_  128
#define NP_  128
#define E_   4096

// ---------------------------------------------------------------------------
// Math: num[b] = sum_e w_e * (P[b,i]·A·P[b,j]) = <Q, R>  with
//       Q = P[b] @ A        (128x128x128 per batch)
//       R = W[b] @ P[b]     (W[i][j] = sum of w_e over edges (i,j); LDS-only)
//       den[b] = sum_e w_e
//       loss = -(1/B) sum_b num[b]/max(den[b],1e-8)
//
// ws layout (bytes):
//   [0, 65536)        A_fid f32 [128][128]
//   [65536, +2048)    num_part[512] f32   (one per k_main block)
//   [67584, +256)     den[64] f32
// ---------------------------------------------------------------------------

// K1: build A_fid (split across 64 blocks) + den[b] = sum of edge_weights row.
__global__ __launch_bounds__(256) void k_prep(
    const float* __restrict__ d_error,
    const int*   __restrict__ d_hw,
    const float* __restrict__ ew,
    float* __restrict__ A,
    float* __restrict__ den)
{
    const int b = blockIdx.x;           // 64 blocks
    const int t = threadIdx.x;

    // A chunk: 256 elements per block
    int idx = b * 256 + t;
    float a = 0.0f;
    if (d_hw[idx] == 1) a = fmaxf(1.0f - d_error[idx], 0.0f);
    A[idx] = a;

    // den[b]: reduce ew[b, 0:4096]
    const float4* ew4 = (const float4*)(ew + b * E_);
    float s = 0.0f;
    #pragma unroll
    for (int k = 0; k < 4; ++k) {
        float4 v = ew4[k * 256 + t];
        s += v.x + v.y + v.z + v.w;
    }
    #pragma unroll
    for (int off = 32; off >= 1; off >>= 1) s += __shfl_xor(s, off, 64);
    __shared__ float rs[4];
    if ((t & 63) == 0) rs[t >> 6] = s;
    __syncthreads();
    if (t == 0) den[b] = rs[0] + rs[1] + rs[2] + rs[3];
}

// K2: per (batch, 16-row chunk): Q rows in regs, W-slab in LDS via edge scan,
// R rows via W @ P_lds, partial num = <Q,R>.  512 blocks = 64 x 8.
__global__ __launch_bounds__(256) void k_main(
    const float* __restrict__ P,
    const float* __restrict__ A,
    const float* __restrict__ ew,
    const int*   __restrict__ pairs_raw,
    float* __restrict__ num_part)
{
    __shared__ float Plds[NL_ * NP_];   // 64 KB  [l'][q] row-major
    __shared__ float WT[NL_ * 16];      // 8 KB   [j][i_local]
    __shared__ float red[4];

    const int b     = blockIdx.x >> 3;
    const int chunk = blockIdx.x & 7;
    const int r0    = chunk * 16;
    const int t  = threadIdx.x;
    const int tr = t >> 5;              // 0..7 -> rows 2tr, 2tr+1 (local)
    const int tc = t & 31;              // cols 4tc..4tc+3

    // zero W-slab (512 float4)
    float4* WT4 = (float4*)WT;
    WT4[2*t]     = float4{0,0,0,0};
    WT4[2*t + 1] = float4{0,0,0,0};

    // stage P[b] -> LDS (4096 float4)
    const float4* Pg4 = (const float4*)(P + (size_t)b * NL_ * NP_);
    float4* Pl4 = (float4*)Plds;
    #pragma unroll
    for (int k = 0; k < 16; ++k) {
        int f = k * 256 + t;
        Pl4[f] = Pg4[f];
    }
    __syncthreads();

    // int64-vs-int32 detection: high words of first 64 values all zero <=> int64
    int hw = pairs_raw[2 * (t & 63) + 1];
    unsigned long long nz = __ballot(hw != 0);
    const int is64 = (nz == 0ULL);

    // edge scan + scatter into W-slab (atomics hidden under Q-phase)
    const float* wrow = ew + (size_t)b * E_;
    if (is64) {
        const int4* pp = (const int4*)pairs_raw + (size_t)b * E_;
        #pragma unroll 4
        for (int k = 0; k < 16; ++k) {
            int e = k * 256 + t;
            int4 pr = pp[e];
            int i = pr.x, j = pr.z;
            if (i >= r0 && i < r0 + 16)
                atomicAdd(&WT[j * 16 + (i - r0)], wrow[e]);
        }
    } else {
        const int2* pp = (const int2*)pairs_raw + (size_t)b * E_;
        #pragma unroll 4
        for (int k = 0; k < 16; ++k) {
            int e = k * 256 + t;
            int2 pr = pp[e];
            int i = pr.x, j = pr.y;
            if (i >= r0 && i < r0 + 16)
                atomicAdd(&WT[j * 16 + (i - r0)], wrow[e]);
        }
    }

    // Q-phase (global-only; overlaps atomic drain): Q[l][4tc..] for l = r0+2tr+{0,1}
    const float* Pr0 = P + ((size_t)b * NL_ + r0 + 2*tr) * NP_;
    const float* Pr1 = Pr0 + NP_;
    const float4* A4 = (const float4*)A;
    float4 q0 = {0,0,0,0}, q1 = {0,0,0,0};
    #pragma unroll 8
    for (int p = 0; p < NP_; ++p) {
        float4 av = A4[p * 32 + tc];
        float pv0 = Pr0[p];
        float pv1 = Pr1[p];
        q0.x = fmaf(pv0, av.x, q0.x); q0.y = fmaf(pv0, av.y, q0.y);
        q0.z = fmaf(pv0, av.z, q0.z); q0.w = fmaf(pv0, av.w, q0.w);
        q1.x = fmaf(pv1, av.x, q1.x); q1.y = fmaf(pv1, av.y, q1.y);
        q1.z = fmaf(pv1, av.z, q1.z); q1.w = fmaf(pv1, av.w, q1.w);
    }
    __syncthreads();   // W-slab complete

    // R-phase: R[l][4tc..] = sum_l' W[l][l'] * Plds[l'][4tc..]
    float4 racc0 = {0,0,0,0}, racc1 = {0,0,0,0};
    const float2* WT2 = (const float2*)WT;
    const float4* Pl4r = (const float4*)Plds;
    #pragma unroll 8
    for (int lp = 0; lp < NL_; ++lp) {
        float2 w01 = WT2[lp * 8 + tr];          // W[2tr][lp], W[2tr+1][lp]
        float4 pv  = Pl4r[lp * 32 + tc];
        racc0.x = fmaf(w01.x, pv.x, racc0.x); racc0.y = fmaf(w01.x, pv.y, racc0.y);
        racc0.z = fmaf(w01.x, pv.z, racc0.z); racc0.w = fmaf(w01.x, pv.w, racc0.w);
        racc1.x = fmaf(w01.y, pv.x, racc1.x); racc1.y = fmaf(w01.y, pv.y, racc1.y);
        racc1.z = fmaf(w01.y, pv.z, racc1.z); racc1.w = fmaf(w01.y, pv.w, racc1.w);
    }

    // partial num = <Q, R> over this thread's 16 cells
    float nacc = q0.x*racc0.x + q0.y*racc0.y + q0.z*racc0.z + q0.w*racc0.w
               + q1.x*racc1.x + q1.y*racc1.y + q1.z*racc1.z + q1.w*racc1.w;
    #pragma unroll
    for (int off = 32; off >= 1; off >>= 1) nacc += __shfl_xor(nacc, off, 64);
    if ((t & 63) == 0) red[t >> 6] = nacc;
    __syncthreads();
    if (t == 0) num_part[blockIdx.x] = red[0] + red[1] + red[2] + red[3];
}

// K3: loss = -(1/B) * sum_b (sum_c num[b,c]) / max(den[b], 1e-8)
__global__ __launch_bounds__(64) void k_final(
    const float* __restrict__ num_part,
    const float* __restrict__ den,
    float* __restrict__ out)
{
    int b = threadIdx.x;
    float n = 0.0f;
    #pragma unroll
    for (int c = 0; c < 8; ++c) n += num_part[b * 8 + c];
    float v = n / fmaxf(den[b], 1e-8f);
    #pragma unroll
    for (int off = 32; off >= 1; off >>= 1) v += __shfl_xor(v, off, 64);
    if (b == 0) out[0] = -v / (float)B_;
}

extern "C" void kernel_launch(void* const* d_in, const int* in_sizes, int n_in,
                              void* d_out, int out_size, void* d_ws, size_t ws_size,
                              hipStream_t stream) {
    const float* P       = (const float*)d_in[0];
    const float* d_error = (const float*)d_in[1];
    const float* ew      = (const float*)d_in[2];
    const int*   d_hw    = (const int*)d_in[3];
    const int*   pairs   = (const int*)d_in[4];
    float* out = (float*)d_out;

    char*  ws  = (char*)d_ws;
    float* A   = (float*)ws;
    float* num = (float*)(ws + 65536);
    float* den = (float*)(ws + 65536 + 2048);

    k_prep <<<64,  256, 0, stream>>>(d_error, d_hw, ew, A, den);
    k_main <<<512, 256, 0, stream>>>(P, A, ew, pairs, num);
    k_final<<<1,   64,  0, stream>>>(num, den, out);
}